// Round 1
// baseline (680.806 us; speedup 1.0000x reference)
//
#include <hip/hip_runtime.h>

typedef short short8 __attribute__((ext_vector_type(8)));
typedef float f32x4 __attribute__((ext_vector_type(4)));
typedef float fv2 __attribute__((ext_vector_type(2)));
typedef unsigned int u32;

#define HDIM 128
#define NSPLIT 32
#define CAP 64          // bucket capacity per row; rows ~Poisson(16), P(>64) ~ 1e-20

#define AS1 __attribute__((address_space(1)))
#define AS3 __attribute__((address_space(3)))

__device__ __forceinline__ void gload16(const void* g, void* l) {
  __builtin_amdgcn_global_load_lds((AS1 const u32*)g, (AS3 u32*)l, 16, 0, 0);
}

__device__ __forceinline__ unsigned short f2bf(float x) {
  unsigned int u = __float_as_uint(x);
  unsigned int r = (u + 0x7fffu + ((u >> 16) & 1u)) >> 16;
  return (unsigned short)r;
}
__device__ __forceinline__ float bf2f(unsigned short b) {
  return __uint_as_float(((unsigned int)b) << 16);
}

#define MFMA(a, b, c) __builtin_amdgcn_mfma_f32_16x16x32_bf16(a, b, c, 0, 0, 0)

// ---------------------------------------------------------------------------
// 1) bucket placement: single pass, p = atomicAdd(cnt[r]); se[r*CAP+p]={c,v}.
//    nt loads on edge stream, nt store on scattered se write (don't pollute L2).
// ---------------------------------------------------------------------------
__global__ __launch_bounds__(256) void bucket_kernel(
    const int* __restrict__ r0, const int* __restrict__ c0, const float* __restrict__ v0,
    const int* __restrict__ r1, const int* __restrict__ c1, const float* __restrict__ v1,
    int* __restrict__ cnt0, int* __restrict__ cnt1,
    long long* __restrict__ se0, long long* __restrict__ se1, int E)
{
  int t = blockIdx.x * 256 + threadIdx.x;
  if (t < E) {
    int r = __builtin_nontemporal_load(r0 + t);
    int c = __builtin_nontemporal_load(c0 + t);
    float v = __builtin_nontemporal_load(v0 + t);
    int p = atomicAdd(&cnt0[r], 1);
    if (p < CAP) {
      long long pk = (long long)(u32)c | ((long long)__float_as_int(v) << 32);
      __builtin_nontemporal_store(pk, se0 + (size_t)r * CAP + p);
    }
  } else if (t < 2 * E) {
    int e = t - E;
    int r = __builtin_nontemporal_load(r1 + e);
    int c = __builtin_nontemporal_load(c1 + e);
    float v = __builtin_nontemporal_load(v1 + e);
    int p = atomicAdd(&cnt1[r], 1);
    if (p < CAP) {
      long long pk = (long long)(u32)c | ((long long)__float_as_int(v) << 32);
      __builtin_nontemporal_store(pk, se1 + (size_t)r * CAP + p);
    }
  }
}

// ---------------------------------------------------------------------------
// 2) gather pass: neigh[v, hc*16..+15] for one (branch, h-chunk).
//    hc = blockIdx&7 == XCD (round-robin) -> per-XCD W_n slice ~3.8 MB (both
//    branches), L2-resident. nt on se reads + neigh writes so the streaming
//    traffic doesn't evict the Wn slice. hc==0 blocks also write deg[v].
// ---------------------------------------------------------------------------
__global__ __launch_bounds__(256) void gatherA_kernel(
    const float* __restrict__ Wn0, const float* __restrict__ Wn1,
    const int* __restrict__ cnt0, const long long* __restrict__ se0,
    const int* __restrict__ cnt1, const long long* __restrict__ se1,
    float* __restrict__ neigh0, float* __restrict__ neigh1,
    float* __restrict__ deg0, float* __restrict__ deg1, int V)
{
  int bid = blockIdx.x;
  int hc = bid & 7;
  int br = (bid >> 3) & 1;
  int rt = bid >> 4;
  const float* Wn = br ? Wn1 : Wn0;
  const int* cnt  = br ? cnt1 : cnt0;
  const long long* se = br ? se1 : se0;
  float* ng       = br ? neigh1 : neigh0;
  float* dg       = br ? deg1 : deg0;
  int rg  = threadIdx.x >> 4;      // 16 row-groups
  int sub = threadIdx.x & 15;
  int col = hc * 16 + sub;
  #pragma unroll
  for (int rr = 0; rr < 4; ++rr) {
    int v = rt * 64 + rg * 4 + rr;
    if (v < V) {
      int n = cnt[v]; if (n > CAP) n = CAP;
      const long long* sep = se + (size_t)v * CAP;
      float acc = 0.f, dsum = 0.f;
      int i = 0;
      for (; i + 4 <= n; i += 4) {
        long long e0 = __builtin_nontemporal_load(sep + i);
        long long e1 = __builtin_nontemporal_load(sep + i + 1);
        long long e2 = __builtin_nontemporal_load(sep + i + 2);
        long long e3 = __builtin_nontemporal_load(sep + i + 3);
        int c0 = (int)(e0 & 0xffffffffLL), c1 = (int)(e1 & 0xffffffffLL);
        int c2 = (int)(e2 & 0xffffffffLL), c3 = (int)(e3 & 0xffffffffLL);
        float w0 = Wn[(size_t)c0 * HDIM + col];
        float w1 = Wn[(size_t)c1 * HDIM + col];
        float w2 = Wn[(size_t)c2 * HDIM + col];
        float w3 = Wn[(size_t)c3 * HDIM + col];
        float f0 = __int_as_float((int)(e0 >> 32)), f1 = __int_as_float((int)(e1 >> 32));
        float f2 = __int_as_float((int)(e2 >> 32)), f3 = __int_as_float((int)(e3 >> 32));
        dsum += (f0 + f1) + (f2 + f3);
        acc = fmaf(f0, w0, acc); acc = fmaf(f1, w1, acc);
        acc = fmaf(f2, w2, acc); acc = fmaf(f3, w3, acc);
      }
      for (; i < n; ++i) {
        long long e0 = __builtin_nontemporal_load(sep + i);
        int c0 = (int)(e0 & 0xffffffffLL);
        float f0 = __int_as_float((int)(e0 >> 32));
        dsum += f0;
        acc = fmaf(f0, Wn[(size_t)c0 * HDIM + col], acc);
      }
      __builtin_nontemporal_store(acc, ng + (size_t)v * HDIM + col);
      if (hc == 0 && sub == 0) dg[v] = dsum;
    }
  }
}

// ---------------------------------------------------------------------------
// 3) LN + branch-sum + pack to bf16 hi/lo MFMA B-fragment layout.
//    One block per packed GROUP (32 rows): 4 waves x 8 rows each, scatter into
//    a 16 KB LDS tile, then write ph/pl contiguously with float4 stores.
//    Replaces 7.7M scattered 2-byte global stores with coalesced 16B stores.
//    Padding rows of the last group come out zero (LDS pre-zeroed) -> the
//    ph/pl tail memsets are gone.
// ---------------------------------------------------------------------------
__global__ __launch_bounds__(256) void lnpack_kernel(
    const float* __restrict__ W0s, const float* __restrict__ W1s,
    const float* __restrict__ neigh0, const float* __restrict__ neigh1,
    const float* __restrict__ deg0, const float* __restrict__ deg1,
    const float* __restrict__ gamma, const float* __restrict__ beta,
    unsigned short* __restrict__ ph, unsigned short* __restrict__ pl, int V)
{
  __shared__ __align__(16) unsigned short lh[4096];
  __shared__ __align__(16) unsigned short ll[4096];
  int g = blockIdx.x;
  int t = threadIdx.x;
  int wv = t >> 6, lane = t & 63;

  {
    f32x4 z = (f32x4)(0.f);
    f32x4* A = (f32x4*)lh;
    f32x4* Bv = (f32x4*)ll;
    #pragma unroll
    for (int i = 0; i < 2; ++i) { A[t + 256 * i] = z; Bv[t + 256 * i] = z; }
  }
  __syncthreads();

  int h = lane * 2;
  fv2 gm = ((const fv2*)gamma)[lane];
  fv2 bt = ((const fv2*)beta)[lane];

  for (int it = 0; it < 8; ++it) {
    int r = wv * 8 + it;           // local row in group, 0..31
    int v = g * 32 + r;
    if (v < V) {
      float ry0 = 0.f, ry1 = 0.f;
      size_t base = (size_t)v * HDIM + h;
      #pragma unroll
      for (int br = 0; br < 2; ++br) {
        const float* Ws = br ? W1s : W0s;
        const float* ng = br ? neigh1 : neigh0;
        const float* dg = br ? deg1 : deg0;
        float invd = 1.0f / fmaxf(dg[v], 1.0f);
        fv2 nn = __builtin_nontemporal_load((const fv2*)(ng + base));
        fv2 ww = __builtin_nontemporal_load((const fv2*)(Ws + base));
        float x0 = fmaxf(fmaf(nn.x, invd, ww.x), 0.f);
        float x1 = fmaxf(fmaf(nn.y, invd, ww.y), 0.f);
        float sum = x0 + x1;
        #pragma unroll
        for (int off = 32; off; off >>= 1) sum += __shfl_xor(sum, off, 64);
        float mu = sum * (1.0f / 128.0f);
        float d0 = x0 - mu, d1 = x1 - mu;
        float q = d0 * d0 + d1 * d1;
        #pragma unroll
        for (int off = 32; off; off >>= 1) q += __shfl_xor(q, off, 64);
        float rstd = rsqrtf(q * (1.0f / 128.0f) + 1e-5f);
        ry0 += d0 * rstd * gm.x + bt.x;
        ry1 += d1 * rstd * gm.y + bt.y;
      }
      // local fragment offset within group (== old global formula - g*4096,
      // valid since (v>>3)&3 == (r>>3)&3 for v = 32g + r)
      int j = r & 7, qq = r >> 3;
      int tt = lane >> 3;
      int l = qq * 16 + (h & 15);
      int loc = tt * 512 + l * 8 + j;
      unsigned short h0 = f2bf(ry0);
      unsigned short l0 = f2bf(ry0 - bf2f(h0));
      unsigned short h1 = f2bf(ry1);
      unsigned short l1 = f2bf(ry1 - bf2f(h1));
      lh[loc] = h0;     ll[loc] = l0;
      lh[loc + 8] = h1; ll[loc + 8] = l1;
    }
  }
  __syncthreads();

  const f32x4* A = (const f32x4*)lh;
  const f32x4* Bv = (const f32x4*)ll;
  f32x4* gh = (f32x4*)(ph + (size_t)g * 4096);
  f32x4* gl = (f32x4*)(pl + (size_t)g * 4096);
  #pragma unroll
  for (int i = 0; i < 2; ++i) {
    gh[t + 256 * i] = A[t + 256 * i];
    gl[t + 256 * i] = Bv[t + 256 * i];
  }
}

__device__ __forceinline__ void cvt8hi(float4 a0, float4 a1, short8& hi) {
  float vv[8] = {a0.x, a0.y, a0.z, a0.w, a1.x, a1.y, a1.z, a1.w};
  #pragma unroll
  for (int j = 0; j < 8; ++j) hi[j] = (short)f2bf(vv[j]);
}

// ---------------------------------------------------------------------------
// 4) MFMA GEMM: global_load_lds(16B) staging of X (fp32, chunk-XOR swizzled)
//    and pre-packed B hi/lo, double-buffered LDS. 2-term split:
//    X(bf16) x (B_hi + B_lo). BM=128, BN=128, K-step 32. Split-K into P.
//    (unchanged this round)
// ---------------------------------------------------------------------------
__global__ __launch_bounds__(256, 2) void gemm_kernel(
    const float* __restrict__ X, const unsigned short* __restrict__ ph,
    const unsigned short* __restrict__ pl, float* __restrict__ P,
    int M, int K, int groups, int gps)
{
  __shared__ __align__(16) float Xl[2][128 * 32];            // 16 KB each
  __shared__ __align__(16) unsigned short Bl[2][2][4096];    // hi/lo, 8 KB each
  int t = threadIdx.x;
  int w = t >> 6, lane = t & 63;
  int m0 = blockIdx.x * 128;
  int g0 = blockIdx.y * gps;
  int g1 = g0 + gps; if (g1 > groups) g1 = groups;
  int q = lane >> 4;

  int xr = w * 32 + (lane >> 3);          // local row for staging call j=0 (+8j)
  int xc = lane & 7;                      // 16B chunk index
  int swz = ((xc ^ (xr & 7)) << 2);

  f32x4 acc[2][8];
  #pragma unroll
  for (int rt = 0; rt < 2; ++rt)
    #pragma unroll
    for (int ct = 0; ct < 8; ++ct) acc[rt][ct] = (f32x4)(0.f);

  auto stageX = [&](int g, int buf) {
    int kf = g * 32 + swz;
    bool ok = (kf + 4 <= K);
    const float* rbase = X + (size_t)(m0 + xr) * K + kf;
    #pragma unroll
    for (int j = 0; j < 4; ++j) {
      const float* gp = ok ? (rbase + (size_t)(8 * j) * K) : X;
      gload16(gp, &Xl[buf][(w * 32 + 8 * j) * 32]);
    }
  };
  auto stageB = [&](int g, int buf) {
    const unsigned short* gh = ph + (size_t)g * 4096 + (w * 2) * 512 + lane * 8;
    const unsigned short* gl = pl + (size_t)g * 4096 + (w * 2) * 512 + lane * 8;
    #pragma unroll
    for (int j = 0; j < 2; ++j) {
      gload16(gh + j * 512, &Bl[buf][0][(w * 2 + j) * 512]);
      gload16(gl + j * 512, &Bl[buf][1][(w * 2 + j) * 512]);
    }
  };

  if (g0 < g1) { stageX(g0, 0); stageB(g0, 0); }
  __syncthreads();

  for (int g = g0; g < g1; ++g) {
    int buf = (g - g0) & 1;
    if (g + 1 < g1) { stageX(g + 1, buf ^ 1); stageB(g + 1, buf ^ 1); }
    short8 ah[2];
    #pragma unroll
    for (int rt = 0; rt < 2; ++rt) {
      int arow = w * 32 + rt * 16 + (lane & 15);
      int sx = arow & 7;
      float4 a0 = *(const float4*)&Xl[buf][arow * 32 + (((2 * q) ^ sx) << 2)];
      float4 a1 = *(const float4*)&Xl[buf][arow * 32 + ((((2 * q) | 1) ^ sx) << 2)];
      cvt8hi(a0, a1, ah[rt]);
    }
    #pragma unroll
    for (int ct = 0; ct < 8; ++ct) {
      short8 bh = *(const short8*)&Bl[buf][0][ct * 512 + lane * 8];
      short8 bl = *(const short8*)&Bl[buf][1][ct * 512 + lane * 8];
      #pragma unroll
      for (int rt = 0; rt < 2; ++rt) {
        acc[rt][ct] = MFMA(ah[rt], bh, acc[rt][ct]);
        acc[rt][ct] = MFMA(ah[rt], bl, acc[rt][ct]);
      }
    }
    __syncthreads();
  }

  float* pp = P + (size_t)blockIdx.y * ((size_t)M * 128);
  #pragma unroll
  for (int rt = 0; rt < 2; ++rt) {
    #pragma unroll
    for (int ct = 0; ct < 8; ++ct) {
      int n = ct * 16 + (lane & 15);
      #pragma unroll
      for (int r = 0; r < 4; ++r) {
        int m = m0 + w * 32 + rt * 16 + (lane >> 4) * 4 + r;
        pp[(size_t)m * 128 + n] = acc[rt][ct][r];
      }
    }
  }
}

// ---------------------------------------------------------------------------
// 5) fused split-K reduce + fc: T-row segment reduced in registers (same
//    s=0..S order as before -> bit-identical), staged through LDS, then
//    out = T @ fc_W + fc_b. Saves the T round-trip and a launch.
// ---------------------------------------------------------------------------
__global__ __launch_bounds__(256) void fc_kernel(
    const float* __restrict__ P, const float* __restrict__ W,
    const float* __restrict__ bias, float* __restrict__ out, int n, int S)
{
  __shared__ float Wl[HDIM * HDIM];   // 64 KB
  __shared__ float Tl[16 * HDIM];     // 8 KB
  int t = threadIdx.x;
  const float4* Wv = (const float4*)W;
  float4* Wlv = (float4*)Wl;
  #pragma unroll
  for (int i = t; i < HDIM * HDIM / 4; i += 256) Wlv[i] = Wv[i];

  int m_loc = t >> 4;                 // 0..15
  int o = (t & 15) << 3;              // 0,8,..,120
  int m = blockIdx.x * 16 + m_loc;
  size_t base = (size_t)m * HDIM + o;

  float4 tv0 = make_float4(0.f, 0.f, 0.f, 0.f);
  float4 tv1 = make_float4(0.f, 0.f, 0.f, 0.f);
  for (int s = 0; s < S; ++s) {
    const float4* pr = (const float4*)(P + (size_t)s * n + base);
    float4 a = pr[0], b = pr[1];
    tv0.x += a.x; tv0.y += a.y; tv0.z += a.z; tv0.w += a.w;
    tv1.x += b.x; tv1.y += b.y; tv1.z += b.z; tv1.w += b.w;
  }
  ((float4*)&Tl[m_loc * HDIM + o])[0] = tv0;
  ((float4*)&Tl[m_loc * HDIM + o])[1] = tv1;
  __syncthreads();

  float acc[8];
  #pragma unroll
  for (int j = 0; j < 8; ++j) acc[j] = bias[o + j];
  const float* Trow = Tl + m_loc * HDIM;
  for (int k = 0; k < HDIM; ++k) {
    float a = Trow[k];
    const float* wr = &Wl[k * HDIM + o];
    #pragma unroll
    for (int j = 0; j < 8; ++j) acc[j] = fmaf(a, wr[j], acc[j]);
  }
  float* orow = out + (size_t)m * HDIM + o;
  #pragma unroll
  for (int j = 0; j < 8; ++j) orow[j] = acc[j];
}

// ---------------------------------------------------------------------------
extern "C" void kernel_launch(void* const* d_in, const int* in_sizes, int n_in,
                              void* d_out, int out_size, void* d_ws, size_t ws_size,
                              hipStream_t stream) {
  const float* X   = (const float*)d_in[0];
  const float* W0s = (const float*)d_in[1];
  const float* W0n = (const float*)d_in[2];
  const float* W1s = (const float*)d_in[3];
  const float* W1n = (const float*)d_in[4];
  const int*   r0  = (const int*)d_in[5];
  const int*   c0  = (const int*)d_in[6];
  const float* v0  = (const float*)d_in[7];
  const int*   r1  = (const int*)d_in[8];
  const int*   c1  = (const int*)d_in[9];
  const float* v1  = (const float*)d_in[10];
  const float* gam = (const float*)d_in[11];
  const float* bet = (const float*)d_in[12];
  const float* fcW = (const float*)d_in[13];
  const float* fcb = (const float*)d_in[14];
  float* out = (float*)d_out;

  const int H = HDIM;
  const int V = in_sizes[1] / H;     // 30000
  const int B = in_sizes[0] / V;     // 2048
  const int E = in_sizes[5];         // 480000
  const int groups = (V + 31) / 32;  // 938

  // workspace layout
  char* p = (char*)d_ws;
  int*   cnt0 = (int*)p;               p += (size_t)V * 4;   // memset covers cnt0+cnt1
  int*   cnt1 = (int*)p;               p += (size_t)V * 4;
  float* deg0 = (float*)p;             p += (size_t)V * 4;   // plain stores, no memset
  float* deg1 = (float*)p;             p += (size_t)V * 4;
  unsigned short* ph = (unsigned short*)p;  p += (size_t)groups * 4096 * 2;
  unsigned short* pl = (unsigned short*)p;  p += (size_t)groups * 4096 * 2;
  // region2: bucket/neigh buffers, later aliased by split-K partials P
  char*  region2 = p;
  long long* se0 = (long long*)region2;                            // V*CAP*8
  long long* se1 = se0 + (size_t)V * CAP;                          // V*CAP*8
  float* neigh0 = (float*)(se1 + (size_t)V * CAP);                 // V*H*4
  float* neigh1 = neigh0 + (size_t)V * H;                          // V*H*4
  float* P      = (float*)region2;     // NSPLIT*B*H*4 = 32 MB <= region

  const int S = NSPLIT;
  const int gps = (groups + S - 1) / S;

  hipMemsetAsync(cnt0, 0, (size_t)V * 2 * 4, stream);

  int eblocks = (2 * E + 255) / 256;
  bucket_kernel<<<eblocks, 256, 0, stream>>>(r0, c0, v0, r1, c1, v1,
                                             cnt0, cnt1, se0, se1, E);
  int rowtiles = (V + 63) / 64;
  gatherA_kernel<<<rowtiles * 16, 256, 0, stream>>>(W0n, W1n,
                                                    cnt0, se0, cnt1, se1,
                                                    neigh0, neigh1, deg0, deg1, V);
  lnpack_kernel<<<groups, 256, 0, stream>>>(W0s, W1s, neigh0, neigh1,
                                            deg0, deg1, gam, bet, ph, pl, V);
  dim3 ggrid(B / 128, S);
  gemm_kernel<<<ggrid, 256, 0, stream>>>(X, ph, pl, P, B, V, groups, gps);
  fc_kernel<<<B / 16, 256, 0, stream>>>(P, fcW, fcb, out, B * H, S);
}

// Round 2
// 605.417 us; speedup vs baseline: 1.1245x; 1.1245x over previous
//
#include <hip/hip_runtime.h>

typedef short short8 __attribute__((ext_vector_type(8)));
typedef float f32x4 __attribute__((ext_vector_type(4)));
typedef float fv2 __attribute__((ext_vector_type(2)));
typedef unsigned int u32;

#define HDIM 128
#define NSPLIT 32
#define CAP 64          // bucket capacity per row; rows ~Poisson(16), P(>64) ~ 1e-20

#define AS1 __attribute__((address_space(1)))
#define AS3 __attribute__((address_space(3)))

__device__ __forceinline__ void gload16(const void* g, void* l) {
  __builtin_amdgcn_global_load_lds((AS1 const u32*)g, (AS3 u32*)l, 16, 0, 0);
}

__device__ __forceinline__ unsigned short f2bf(float x) {
  unsigned int u = __float_as_uint(x);
  unsigned int r = (u + 0x7fffu + ((u >> 16) & 1u)) >> 16;
  return (unsigned short)r;
}
__device__ __forceinline__ float bf2f(unsigned short b) {
  return __uint_as_float(((unsigned int)b) << 16);
}

#define MFMA(a, b, c) __builtin_amdgcn_mfma_f32_16x16x32_bf16(a, b, c, 0, 0, 0)

// ---------------------------------------------------------------------------
// 1) bucket placement: single pass, p = atomicAdd(cnt[r]); se[r*CAP+p]={c,v}.
//    Plain stores (round-0 semantics): se stays L2/L3-resident for gather.
//    [R1 post-mortem: nontemporal hints pushed se to HBM -> gather FETCH 375MB]
// ---------------------------------------------------------------------------
__global__ __launch_bounds__(256) void bucket_kernel(
    const int* __restrict__ r0, const int* __restrict__ c0, const float* __restrict__ v0,
    const int* __restrict__ r1, const int* __restrict__ c1, const float* __restrict__ v1,
    int* __restrict__ cnt0, int* __restrict__ cnt1,
    int2* __restrict__ se0, int2* __restrict__ se1, int E)
{
  int t = blockIdx.x * 256 + threadIdx.x;
  if (t < E) {
    int r = r0[t];
    int p = atomicAdd(&cnt0[r], 1);
    if (p < CAP) se0[(size_t)r * CAP + p] = make_int2(c0[t], __float_as_int(v0[t]));
  } else if (t < 2 * E) {
    int e = t - E;
    int r = r1[e];
    int p = atomicAdd(&cnt1[r], 1);
    if (p < CAP) se1[(size_t)r * CAP + p] = make_int2(c1[e], __float_as_int(v1[e]));
  }
}

// ---------------------------------------------------------------------------
// 2) gather pass: neigh[v, hc*16..+15] for one (branch, h-chunk).
//    hc = blockIdx&7 == XCD (round-robin) -> per-XCD W_n slice, L2/L3-served.
//    Plain loads/stores (round-0 semantics). hc==0 blocks also write deg[v].
// ---------------------------------------------------------------------------
__global__ __launch_bounds__(256) void gatherA_kernel(
    const float* __restrict__ Wn0, const float* __restrict__ Wn1,
    const int* __restrict__ cnt0, const int2* __restrict__ se0,
    const int* __restrict__ cnt1, const int2* __restrict__ se1,
    float* __restrict__ neigh0, float* __restrict__ neigh1,
    float* __restrict__ deg0, float* __restrict__ deg1, int V)
{
  int bid = blockIdx.x;
  int hc = bid & 7;
  int br = (bid >> 3) & 1;
  int rt = bid >> 4;
  const float* Wn = br ? Wn1 : Wn0;
  const int* cnt  = br ? cnt1 : cnt0;
  const int2* se  = br ? se1 : se0;
  float* ng       = br ? neigh1 : neigh0;
  float* dg       = br ? deg1 : deg0;
  int rg  = threadIdx.x >> 4;      // 16 row-groups
  int sub = threadIdx.x & 15;
  int col = hc * 16 + sub;
  #pragma unroll
  for (int rr = 0; rr < 4; ++rr) {
    int v = rt * 64 + rg * 4 + rr;
    if (v < V) {
      int n = cnt[v]; if (n > CAP) n = CAP;
      size_t s0 = (size_t)v * CAP;
      float acc = 0.f, dsum = 0.f;
      int i = 0;
      for (; i + 4 <= n; i += 4) {
        int2 e0 = se[s0 + i], e1 = se[s0 + i + 1], e2 = se[s0 + i + 2], e3 = se[s0 + i + 3];
        float w0 = Wn[(size_t)e0.x * HDIM + col];
        float w1 = Wn[(size_t)e1.x * HDIM + col];
        float w2 = Wn[(size_t)e2.x * HDIM + col];
        float w3 = Wn[(size_t)e3.x * HDIM + col];
        float f0 = __int_as_float(e0.y), f1 = __int_as_float(e1.y);
        float f2 = __int_as_float(e2.y), f3 = __int_as_float(e3.y);
        dsum += (f0 + f1) + (f2 + f3);
        acc = fmaf(f0, w0, acc); acc = fmaf(f1, w1, acc);
        acc = fmaf(f2, w2, acc); acc = fmaf(f3, w3, acc);
      }
      for (; i < n; ++i) {
        int2 e0 = se[s0 + i];
        float f0 = __int_as_float(e0.y);
        dsum += f0;
        acc = fmaf(f0, Wn[(size_t)e0.x * HDIM + col], acc);
      }
      ng[(size_t)v * HDIM + col] = acc;
      if (hc == 0 && sub == 0) dg[v] = dsum;
    }
  }
}

// ---------------------------------------------------------------------------
// 3) LN + branch-sum + pack to bf16 hi/lo MFMA B-fragment layout.
//    One 1024-thread block per packed GROUP (32 rows): 16 waves x 2 rows each,
//    scatter into 16 KB LDS tile, then write ph/pl contiguously (16B stores).
//    Replaces 7.7M scattered 2-byte global stores with coalesced stores while
//    keeping ~1M-thread parallelism (R1's 4-wave version serialized 8 rows).
//    Padding rows of the last group come out zero (LDS pre-zeroed).
// ---------------------------------------------------------------------------
__global__ __launch_bounds__(1024) void lnpack_kernel(
    const float* __restrict__ W0s, const float* __restrict__ W1s,
    const float* __restrict__ neigh0, const float* __restrict__ neigh1,
    const float* __restrict__ deg0, const float* __restrict__ deg1,
    const float* __restrict__ gamma, const float* __restrict__ beta,
    unsigned short* __restrict__ ph, unsigned short* __restrict__ pl, int V)
{
  __shared__ __align__(16) unsigned short lh[4096];
  __shared__ __align__(16) unsigned short ll[4096];
  int g = blockIdx.x;
  int t = threadIdx.x;
  int wv = t >> 6, lane = t & 63;

  {
    f32x4 z = (f32x4)(0.f);
    if (t < 512) ((f32x4*)lh)[t] = z;
    else         ((f32x4*)ll)[t - 512] = z;
  }
  __syncthreads();

  int h = lane * 2;
  fv2 gm = ((const fv2*)gamma)[lane];
  fv2 bt = ((const fv2*)beta)[lane];

  #pragma unroll
  for (int it = 0; it < 2; ++it) {
    int r = it * 16 + wv;          // local row in group, 0..31
    int v = g * 32 + r;
    if (v < V) {
      float ry0 = 0.f, ry1 = 0.f;
      size_t base = (size_t)v * HDIM + h;
      #pragma unroll
      for (int br = 0; br < 2; ++br) {
        const float* Ws = br ? W1s : W0s;
        const float* ng = br ? neigh1 : neigh0;
        const float* dg = br ? deg1 : deg0;
        float invd = 1.0f / fmaxf(dg[v], 1.0f);
        fv2 nn = *(const fv2*)(ng + base);
        fv2 ww = *(const fv2*)(Ws + base);
        float x0 = fmaxf(fmaf(nn.x, invd, ww.x), 0.f);
        float x1 = fmaxf(fmaf(nn.y, invd, ww.y), 0.f);
        float sum = x0 + x1;
        #pragma unroll
        for (int off = 32; off; off >>= 1) sum += __shfl_xor(sum, off, 64);
        float mu = sum * (1.0f / 128.0f);
        float d0 = x0 - mu, d1 = x1 - mu;
        float q = d0 * d0 + d1 * d1;
        #pragma unroll
        for (int off = 32; off; off >>= 1) q += __shfl_xor(q, off, 64);
        float rstd = rsqrtf(q * (1.0f / 128.0f) + 1e-5f);
        ry0 += d0 * rstd * gm.x + bt.x;
        ry1 += d1 * rstd * gm.y + bt.y;
      }
      // local fragment offset within group (== old global formula - g*4096,
      // valid since (v>>3)&3 == (r>>3)&3 for v = 32g + r)
      int j = r & 7, qq = r >> 3;
      int tt = lane >> 3;
      int l = qq * 16 + (h & 15);
      int loc = tt * 512 + l * 8 + j;
      unsigned short h0 = f2bf(ry0);
      unsigned short l0 = f2bf(ry0 - bf2f(h0));
      unsigned short h1 = f2bf(ry1);
      unsigned short l1 = f2bf(ry1 - bf2f(h1));
      lh[loc] = h0;     ll[loc] = l0;
      lh[loc + 8] = h1; ll[loc + 8] = l1;
    }
  }
  __syncthreads();

  if (t < 512) ((f32x4*)(ph + (size_t)g * 4096))[t]       = ((const f32x4*)lh)[t];
  else         ((f32x4*)(pl + (size_t)g * 4096))[t - 512] = ((const f32x4*)ll)[t - 512];
}

__device__ __forceinline__ void cvt8hi(float4 a0, float4 a1, short8& hi) {
  float vv[8] = {a0.x, a0.y, a0.z, a0.w, a1.x, a1.y, a1.z, a1.w};
  #pragma unroll
  for (int j = 0; j < 8; ++j) hi[j] = (short)f2bf(vv[j]);
}

// ---------------------------------------------------------------------------
// 4) MFMA GEMM: global_load_lds(16B) staging of X (fp32, chunk-XOR swizzled)
//    and pre-packed B hi/lo, double-buffered LDS. 2-term split:
//    X(bf16) x (B_hi + B_lo). BM=128, BN=128, K-step 32. Split-K into P.
//    (unchanged)
// ---------------------------------------------------------------------------
__global__ __launch_bounds__(256, 2) void gemm_kernel(
    const float* __restrict__ X, const unsigned short* __restrict__ ph,
    const unsigned short* __restrict__ pl, float* __restrict__ P,
    int M, int K, int groups, int gps)
{
  __shared__ __align__(16) float Xl[2][128 * 32];            // 16 KB each
  __shared__ __align__(16) unsigned short Bl[2][2][4096];    // hi/lo, 8 KB each
  int t = threadIdx.x;
  int w = t >> 6, lane = t & 63;
  int m0 = blockIdx.x * 128;
  int g0 = blockIdx.y * gps;
  int g1 = g0 + gps; if (g1 > groups) g1 = groups;
  int q = lane >> 4;

  int xr = w * 32 + (lane >> 3);          // local row for staging call j=0 (+8j)
  int xc = lane & 7;                      // 16B chunk index
  int swz = ((xc ^ (xr & 7)) << 2);

  f32x4 acc[2][8];
  #pragma unroll
  for (int rt = 0; rt < 2; ++rt)
    #pragma unroll
    for (int ct = 0; ct < 8; ++ct) acc[rt][ct] = (f32x4)(0.f);

  auto stageX = [&](int g, int buf) {
    int kf = g * 32 + swz;
    bool ok = (kf + 4 <= K);
    const float* rbase = X + (size_t)(m0 + xr) * K + kf;
    #pragma unroll
    for (int j = 0; j < 4; ++j) {
      const float* gp = ok ? (rbase + (size_t)(8 * j) * K) : X;
      gload16(gp, &Xl[buf][(w * 32 + 8 * j) * 32]);
    }
  };
  auto stageB = [&](int g, int buf) {
    const unsigned short* gh = ph + (size_t)g * 4096 + (w * 2) * 512 + lane * 8;
    const unsigned short* gl = pl + (size_t)g * 4096 + (w * 2) * 512 + lane * 8;
    #pragma unroll
    for (int j = 0; j < 2; ++j) {
      gload16(gh + j * 512, &Bl[buf][0][(w * 2 + j) * 512]);
      gload16(gl + j * 512, &Bl[buf][1][(w * 2 + j) * 512]);
    }
  };

  if (g0 < g1) { stageX(g0, 0); stageB(g0, 0); }
  __syncthreads();

  for (int g = g0; g < g1; ++g) {
    int buf = (g - g0) & 1;
    if (g + 1 < g1) { stageX(g + 1, buf ^ 1); stageB(g + 1, buf ^ 1); }
    short8 ah[2];
    #pragma unroll
    for (int rt = 0; rt < 2; ++rt) {
      int arow = w * 32 + rt * 16 + (lane & 15);
      int sx = arow & 7;
      float4 a0 = *(const float4*)&Xl[buf][arow * 32 + (((2 * q) ^ sx) << 2)];
      float4 a1 = *(const float4*)&Xl[buf][arow * 32 + ((((2 * q) | 1) ^ sx) << 2)];
      cvt8hi(a0, a1, ah[rt]);
    }
    #pragma unroll
    for (int ct = 0; ct < 8; ++ct) {
      short8 bh = *(const short8*)&Bl[buf][0][ct * 512 + lane * 8];
      short8 bl = *(const short8*)&Bl[buf][1][ct * 512 + lane * 8];
      #pragma unroll
      for (int rt = 0; rt < 2; ++rt) {
        acc[rt][ct] = MFMA(ah[rt], bh, acc[rt][ct]);
        acc[rt][ct] = MFMA(ah[rt], bl, acc[rt][ct]);
      }
    }
    __syncthreads();
  }

  float* pp = P + (size_t)blockIdx.y * ((size_t)M * 128);
  #pragma unroll
  for (int rt = 0; rt < 2; ++rt) {
    #pragma unroll
    for (int ct = 0; ct < 8; ++ct) {
      int n = ct * 16 + (lane & 15);
      #pragma unroll
      for (int r = 0; r < 4; ++r) {
        int m = m0 + w * 32 + rt * 16 + (lane >> 4) * 4 + r;
        pp[(size_t)m * 128 + n] = acc[rt][ct][r];
      }
    }
  }
}

// ---------------------------------------------------------------------------
// 5) fused split-K reduce + fc: T-row segment reduced in registers (same
//    s=0..S order -> bit-identical), staged through LDS, then
//    out = T @ fc_W + fc_b. Saves the T round-trip and a launch.
// ---------------------------------------------------------------------------
__global__ __launch_bounds__(256) void fc_kernel(
    const float* __restrict__ P, const float* __restrict__ W,
    const float* __restrict__ bias, float* __restrict__ out, int n, int S)
{
  __shared__ float Wl[HDIM * HDIM];   // 64 KB
  __shared__ float Tl[16 * HDIM];     // 8 KB
  int t = threadIdx.x;
  const float4* Wv = (const float4*)W;
  float4* Wlv = (float4*)Wl;
  #pragma unroll
  for (int i = t; i < HDIM * HDIM / 4; i += 256) Wlv[i] = Wv[i];

  int m_loc = t >> 4;                 // 0..15
  int o = (t & 15) << 3;              // 0,8,..,120
  int m = blockIdx.x * 16 + m_loc;
  size_t base = (size_t)m * HDIM + o;

  float4 tv0 = make_float4(0.f, 0.f, 0.f, 0.f);
  float4 tv1 = make_float4(0.f, 0.f, 0.f, 0.f);
  for (int s = 0; s < S; ++s) {
    const float4* pr = (const float4*)(P + (size_t)s * n + base);
    float4 a = pr[0], b = pr[1];
    tv0.x += a.x; tv0.y += a.y; tv0.z += a.z; tv0.w += a.w;
    tv1.x += b.x; tv1.y += b.y; tv1.z += b.z; tv1.w += b.w;
  }
  ((float4*)&Tl[m_loc * HDIM + o])[0] = tv0;
  ((float4*)&Tl[m_loc * HDIM + o])[1] = tv1;
  __syncthreads();

  float acc[8];
  #pragma unroll
  for (int j = 0; j < 8; ++j) acc[j] = bias[o + j];
  const float* Trow = Tl + m_loc * HDIM;
  for (int k = 0; k < HDIM; ++k) {
    float a = Trow[k];
    const float* wr = &Wl[k * HDIM + o];
    #pragma unroll
    for (int j = 0; j < 8; ++j) acc[j] = fmaf(a, wr[j], acc[j]);
  }
  float* orow = out + (size_t)m * HDIM + o;
  #pragma unroll
  for (int j = 0; j < 8; ++j) orow[j] = acc[j];
}

// ---------------------------------------------------------------------------
extern "C" void kernel_launch(void* const* d_in, const int* in_sizes, int n_in,
                              void* d_out, int out_size, void* d_ws, size_t ws_size,
                              hipStream_t stream) {
  const float* X   = (const float*)d_in[0];
  const float* W0s = (const float*)d_in[1];
  const float* W0n = (const float*)d_in[2];
  const float* W1s = (const float*)d_in[3];
  const float* W1n = (const float*)d_in[4];
  const int*   r0  = (const int*)d_in[5];
  const int*   c0  = (const int*)d_in[6];
  const float* v0  = (const float*)d_in[7];
  const int*   r1  = (const int*)d_in[8];
  const int*   c1  = (const int*)d_in[9];
  const float* v1  = (const float*)d_in[10];
  const float* gam = (const float*)d_in[11];
  const float* bet = (const float*)d_in[12];
  const float* fcW = (const float*)d_in[13];
  const float* fcb = (const float*)d_in[14];
  float* out = (float*)d_out;

  const int H = HDIM;
  const int V = in_sizes[1] / H;     // 30000
  const int B = in_sizes[0] / V;     // 2048
  const int E = in_sizes[5];         // 480000
  const int groups = (V + 31) / 32;  // 938

  // workspace layout
  char* p = (char*)d_ws;
  int*   cnt0 = (int*)p;               p += (size_t)V * 4;   // memset covers cnt0+cnt1
  int*   cnt1 = (int*)p;               p += (size_t)V * 4;
  float* deg0 = (float*)p;             p += (size_t)V * 4;   // plain stores, no memset
  float* deg1 = (float*)p;             p += (size_t)V * 4;
  unsigned short* ph = (unsigned short*)p;  p += (size_t)groups * 4096 * 2;
  unsigned short* pl = (unsigned short*)p;  p += (size_t)groups * 4096 * 2;
  // region2: bucket/neigh buffers, later aliased by split-K partials P
  char*  region2 = p;
  int2*  se0    = (int2*)region2;                                  // V*CAP*8
  int2*  se1    = se0 + (size_t)V * CAP;                           // V*CAP*8
  float* neigh0 = (float*)(se1 + (size_t)V * CAP);                 // V*H*4
  float* neigh1 = neigh0 + (size_t)V * H;                          // V*H*4
  float* P      = (float*)region2;     // NSPLIT*B*H*4 = 32 MB <= region

  const int S = NSPLIT;
  const int gps = (groups + S - 1) / S;

  hipMemsetAsync(cnt0, 0, (size_t)V * 2 * 4, stream);

  int eblocks = (2 * E + 255) / 256;
  bucket_kernel<<<eblocks, 256, 0, stream>>>(r0, c0, v0, r1, c1, v1,
                                             cnt0, cnt1, se0, se1, E);
  int rowtiles = (V + 63) / 64;
  gatherA_kernel<<<rowtiles * 16, 256, 0, stream>>>(W0n, W1n,
                                                    cnt0, se0, cnt1, se1,
                                                    neigh0, neigh1, deg0, deg1, V);
  lnpack_kernel<<<groups, 1024, 0, stream>>>(W0s, W1s, neigh0, neigh1,
                                             deg0, deg1, gam, bet, ph, pl, V);
  dim3 ggrid(B / 128, S);
  gemm_kernel<<<ggrid, 256, 0, stream>>>(X, ph, pl, P, B, V, groups, gps);
  fc_kernel<<<B / 16, 256, 0, stream>>>(P, fcW, fcb, out, B * H, S);
}

// Round 3
// 556.300 us; speedup vs baseline: 1.2238x; 1.0883x over previous
//
#include <hip/hip_runtime.h>

typedef short short8 __attribute__((ext_vector_type(8)));
typedef float f32x4 __attribute__((ext_vector_type(4)));
typedef float fv2 __attribute__((ext_vector_type(2)));
typedef unsigned int u32;

#define HDIM 128
#define NSPLIT 32
#define CAP 64          // bucket capacity per row; rows ~Poisson(16), P(>64) ~ 1e-20

#define AS1 __attribute__((address_space(1)))
#define AS3 __attribute__((address_space(3)))

__device__ __forceinline__ void gload16(const void* g, void* l) {
  __builtin_amdgcn_global_load_lds((AS1 const u32*)g, (AS3 u32*)l, 16, 0, 0);
}

__device__ __forceinline__ unsigned short f2bf(float x) {
  unsigned int u = __float_as_uint(x);
  unsigned int r = (u + 0x7fffu + ((u >> 16) & 1u)) >> 16;
  return (unsigned short)r;
}
__device__ __forceinline__ float bf2f(unsigned short b) {
  return __uint_as_float(((unsigned int)b) << 16);
}

#define MFMA(a, b, c) __builtin_amdgcn_mfma_f32_16x16x32_bf16(a, b, c, 0, 0, 0)

// ---------------------------------------------------------------------------
// 1) bucket placement: single pass, p = atomicAdd(cnt[r]); se[r*CAP+p]={c,v}.
//    Plain stores (R0 semantics; R1 showed nt hints push se to HBM).
// ---------------------------------------------------------------------------
__global__ __launch_bounds__(256) void bucket_kernel(
    const int* __restrict__ r0, const int* __restrict__ c0, const float* __restrict__ v0,
    const int* __restrict__ r1, const int* __restrict__ c1, const float* __restrict__ v1,
    int* __restrict__ cnt0, int* __restrict__ cnt1,
    int2* __restrict__ se0, int2* __restrict__ se1, int E)
{
  int t = blockIdx.x * 256 + threadIdx.x;
  if (t < E) {
    int r = r0[t];
    int p = atomicAdd(&cnt0[r], 1);
    if (p < CAP) se0[(size_t)r * CAP + p] = make_int2(c0[t], __float_as_int(v0[t]));
  } else if (t < 2 * E) {
    int e = t - E;
    int r = r1[e];
    int p = atomicAdd(&cnt1[r], 1);
    if (p < CAP) se1[(size_t)r * CAP + p] = make_int2(c1[e], __float_as_int(v1[e]));
  }
}

// ---------------------------------------------------------------------------
// 2) FUSED gather + LN + bf16 hi/lo pack.  [R2->R3 structural change]
//    One wave per vocab row; lane owns cols h=2*lane, 2*lane+1 (lnpack layout,
//    so the shfl-LN + packing code is carried over with identical numeric
//    order: 4-wide dsum/acc quads, two-pass LN).
//    - se/cnt read ONCE per row (old gatherA read them 8x across h-chunks)
//    - neigh (30.7 MB) + deg HBM round-trip eliminated
//    - Wn read as float2 per lane: 512 B/edge, same total bytes as before,
//      served from L3 (Wn0+Wn1 = 30.7 MB, fully L3-resident)
//    - no intra-wave divergence: all 64 lanes share one row's edge count
//    Block = 1024 thr = 16 waves = 16 rows = half a packed group; results are
//    scattered into an 8 KB LDS half-tile and written out coalesced (f32x4).
//    Guarded rows (v >= V, incl. the 30000..30015 K-padding) stay zero via
//    LDS pre-zeroing.
// ---------------------------------------------------------------------------
__global__ __launch_bounds__(1024) void fused_glp_kernel(
    const float* __restrict__ Wn0, const float* __restrict__ Wn1,
    const float* __restrict__ W0s, const float* __restrict__ W1s,
    const int* __restrict__ cnt0, const int2* __restrict__ se0,
    const int* __restrict__ cnt1, const int2* __restrict__ se1,
    const float* __restrict__ gamma, const float* __restrict__ beta,
    unsigned short* __restrict__ ph, unsigned short* __restrict__ pl, int V)
{
  __shared__ __align__(16) unsigned short lh[2048];   // 4 KB hi half-tile
  __shared__ __align__(16) unsigned short ll[2048];   // 4 KB lo half-tile
  int t = threadIdx.x;
  int wv = t >> 6, lane = t & 63;
  int g = blockIdx.x >> 1, hs = blockIdx.x & 1;

  if (t < 256)      ((f32x4*)lh)[t] = (f32x4)(0.f);
  else if (t < 512) ((f32x4*)ll)[t - 256] = (f32x4)(0.f);
  __syncthreads();

  int v = g * 32 + hs * 16 + wv;
  int h = lane * 2;
  if (v < V) {
    fv2 gm = ((const fv2*)gamma)[lane];
    fv2 bt = ((const fv2*)beta)[lane];
    float ry0 = 0.f, ry1 = 0.f;
    #pragma unroll
    for (int br = 0; br < 2; ++br) {
      const float* Wn = br ? Wn1 : Wn0;
      const float* Ws = br ? W1s : W0s;
      const int* cnt  = br ? cnt1 : cnt0;
      const int2* se  = br ? se1 : se0;
      int n = cnt[v]; if (n > CAP) n = CAP;
      const int2* sep = se + (size_t)v * CAP;
      float a0 = 0.f, a1 = 0.f, dsum = 0.f;
      int i = 0;
      for (; i + 4 <= n; i += 4) {
        int2 e0 = sep[i], e1 = sep[i + 1], e2 = sep[i + 2], e3 = sep[i + 3];
        fv2 w0 = ((const fv2*)(Wn + (size_t)e0.x * HDIM))[lane];
        fv2 w1 = ((const fv2*)(Wn + (size_t)e1.x * HDIM))[lane];
        fv2 w2 = ((const fv2*)(Wn + (size_t)e2.x * HDIM))[lane];
        fv2 w3 = ((const fv2*)(Wn + (size_t)e3.x * HDIM))[lane];
        float f0 = __int_as_float(e0.y), f1 = __int_as_float(e1.y);
        float f2 = __int_as_float(e2.y), f3 = __int_as_float(e3.y);
        dsum += (f0 + f1) + (f2 + f3);
        a0 = fmaf(f0, w0.x, a0); a1 = fmaf(f0, w0.y, a1);
        a0 = fmaf(f1, w1.x, a0); a1 = fmaf(f1, w1.y, a1);
        a0 = fmaf(f2, w2.x, a0); a1 = fmaf(f2, w2.y, a1);
        a0 = fmaf(f3, w3.x, a0); a1 = fmaf(f3, w3.y, a1);
      }
      for (; i < n; ++i) {
        int2 e0 = sep[i];
        fv2 w0 = ((const fv2*)(Wn + (size_t)e0.x * HDIM))[lane];
        float f0 = __int_as_float(e0.y);
        dsum += f0;
        a0 = fmaf(f0, w0.x, a0); a1 = fmaf(f0, w0.y, a1);
      }
      float invd = 1.0f / fmaxf(dsum, 1.0f);
      fv2 ww = ((const fv2*)(Ws + (size_t)v * HDIM))[lane];
      float x0 = fmaxf(fmaf(a0, invd, ww.x), 0.f);
      float x1 = fmaxf(fmaf(a1, invd, ww.y), 0.f);
      float sum = x0 + x1;
      #pragma unroll
      for (int off = 32; off; off >>= 1) sum += __shfl_xor(sum, off, 64);
      float mu = sum * (1.0f / 128.0f);
      float d0 = x0 - mu, d1 = x1 - mu;
      float q = d0 * d0 + d1 * d1;
      #pragma unroll
      for (int off = 32; off; off >>= 1) q += __shfl_xor(q, off, 64);
      float rstd = rsqrtf(q * (1.0f / 128.0f) + 1e-5f);
      ry0 += d0 * rstd * gm.x + bt.x;
      ry1 += d1 * rstd * gm.y + bt.y;
    }
    // local scatter into half-tile: full-group slot = tt*512 + l*8 + j with
    // l = qq*16 + (h&15), qq = r>>3, j = r&7, r = hs*16+wv; half-local form:
    int tt = lane >> 3;
    int loc = tt * 256 + ((wv >> 3) * 16 + (h & 15)) * 8 + (wv & 7);
    unsigned short h0 = f2bf(ry0);
    unsigned short l0 = f2bf(ry0 - bf2f(h0));
    unsigned short h1 = f2bf(ry1);
    unsigned short l1 = f2bf(ry1 - bf2f(h1));
    lh[loc] = h0;     ll[loc] = l0;
    lh[loc + 8] = h1; ll[loc + 8] = l1;
  }
  __syncthreads();

  // coalesced write-out: half-tile chunk c (16B) -> global chunk
  //   g*512 + (c>>5)*32 + hs*32 + c     (512 B runs, 512 B stride)
  if (t < 512) {
    int arr = t >> 8;            // 0: ph, 1: pl
    int c = t & 255;
    size_t chunk = (size_t)g * 512 + (size_t)(((c >> 5) + hs) * 32 + c);
    f32x4 val = arr ? ((const f32x4*)ll)[c] : ((const f32x4*)lh)[c];
    f32x4* dst = arr ? (f32x4*)pl : (f32x4*)ph;
    dst[chunk] = val;
  }
}

__device__ __forceinline__ void cvt8hi(float4 a0, float4 a1, short8& hi) {
  float vv[8] = {a0.x, a0.y, a0.z, a0.w, a1.x, a1.y, a1.z, a1.w};
  #pragma unroll
  for (int j = 0; j < 8; ++j) hi[j] = (short)f2bf(vv[j]);
}

// ---------------------------------------------------------------------------
// 3) MFMA GEMM: global_load_lds(16B) staging of X (fp32, chunk-XOR swizzled)
//    and pre-packed B hi/lo, double-buffered LDS. 2-term split:
//    X(bf16) x (B_hi + B_lo). BM=128, BN=128, K-step 32. Split-K into P.
//    (unchanged)
// ---------------------------------------------------------------------------
__global__ __launch_bounds__(256, 2) void gemm_kernel(
    const float* __restrict__ X, const unsigned short* __restrict__ ph,
    const unsigned short* __restrict__ pl, float* __restrict__ P,
    int M, int K, int groups, int gps)
{
  __shared__ __align__(16) float Xl[2][128 * 32];            // 16 KB each
  __shared__ __align__(16) unsigned short Bl[2][2][4096];    // hi/lo, 8 KB each
  int t = threadIdx.x;
  int w = t >> 6, lane = t & 63;
  int m0 = blockIdx.x * 128;
  int g0 = blockIdx.y * gps;
  int g1 = g0 + gps; if (g1 > groups) g1 = groups;
  int q = lane >> 4;

  int xr = w * 32 + (lane >> 3);          // local row for staging call j=0 (+8j)
  int xc = lane & 7;                      // 16B chunk index
  int swz = ((xc ^ (xr & 7)) << 2);

  f32x4 acc[2][8];
  #pragma unroll
  for (int rt = 0; rt < 2; ++rt)
    #pragma unroll
    for (int ct = 0; ct < 8; ++ct) acc[rt][ct] = (f32x4)(0.f);

  auto stageX = [&](int g, int buf) {
    int kf = g * 32 + swz;
    bool ok = (kf + 4 <= K);
    const float* rbase = X + (size_t)(m0 + xr) * K + kf;
    #pragma unroll
    for (int j = 0; j < 4; ++j) {
      const float* gp = ok ? (rbase + (size_t)(8 * j) * K) : X;
      gload16(gp, &Xl[buf][(w * 32 + 8 * j) * 32]);
    }
  };
  auto stageB = [&](int g, int buf) {
    const unsigned short* gh = ph + (size_t)g * 4096 + (w * 2) * 512 + lane * 8;
    const unsigned short* gl = pl + (size_t)g * 4096 + (w * 2) * 512 + lane * 8;
    #pragma unroll
    for (int j = 0; j < 2; ++j) {
      gload16(gh + j * 512, &Bl[buf][0][(w * 2 + j) * 512]);
      gload16(gl + j * 512, &Bl[buf][1][(w * 2 + j) * 512]);
    }
  };

  if (g0 < g1) { stageX(g0, 0); stageB(g0, 0); }
  __syncthreads();

  for (int g = g0; g < g1; ++g) {
    int buf = (g - g0) & 1;
    if (g + 1 < g1) { stageX(g + 1, buf ^ 1); stageB(g + 1, buf ^ 1); }
    short8 ah[2];
    #pragma unroll
    for (int rt = 0; rt < 2; ++rt) {
      int arow = w * 32 + rt * 16 + (lane & 15);
      int sx = arow & 7;
      float4 a0 = *(const float4*)&Xl[buf][arow * 32 + (((2 * q) ^ sx) << 2)];
      float4 a1 = *(const float4*)&Xl[buf][arow * 32 + ((((2 * q) | 1) ^ sx) << 2)];
      cvt8hi(a0, a1, ah[rt]);
    }
    #pragma unroll
    for (int ct = 0; ct < 8; ++ct) {
      short8 bh = *(const short8*)&Bl[buf][0][ct * 512 + lane * 8];
      short8 bl = *(const short8*)&Bl[buf][1][ct * 512 + lane * 8];
      #pragma unroll
      for (int rt = 0; rt < 2; ++rt) {
        acc[rt][ct] = MFMA(ah[rt], bh, acc[rt][ct]);
        acc[rt][ct] = MFMA(ah[rt], bl, acc[rt][ct]);
      }
    }
    __syncthreads();
  }

  float* pp = P + (size_t)blockIdx.y * ((size_t)M * 128);
  #pragma unroll
  for (int rt = 0; rt < 2; ++rt) {
    #pragma unroll
    for (int ct = 0; ct < 8; ++ct) {
      int n = ct * 16 + (lane & 15);
      #pragma unroll
      for (int r = 0; r < 4; ++r) {
        int m = m0 + w * 32 + rt * 16 + (lane >> 4) * 4 + r;
        pp[(size_t)m * 128 + n] = acc[rt][ct][r];
      }
    }
  }
}

// ---------------------------------------------------------------------------
// 4) fused split-K reduce + fc: T-row segment reduced in registers (same
//    s=0..S order -> bit-identical), staged through LDS, then
//    out = T @ fc_W + fc_b. (unchanged)
// ---------------------------------------------------------------------------
__global__ __launch_bounds__(256) void fc_kernel(
    const float* __restrict__ P, const float* __restrict__ W,
    const float* __restrict__ bias, float* __restrict__ out, int n, int S)
{
  __shared__ float Wl[HDIM * HDIM];   // 64 KB
  __shared__ float Tl[16 * HDIM];     // 8 KB
  int t = threadIdx.x;
  const float4* Wv = (const float4*)W;
  float4* Wlv = (float4*)Wl;
  #pragma unroll
  for (int i = t; i < HDIM * HDIM / 4; i += 256) Wlv[i] = Wv[i];

  int m_loc = t >> 4;                 // 0..15
  int o = (t & 15) << 3;              // 0,8,..,120
  int m = blockIdx.x * 16 + m_loc;
  size_t base = (size_t)m * HDIM + o;

  float4 tv0 = make_float4(0.f, 0.f, 0.f, 0.f);
  float4 tv1 = make_float4(0.f, 0.f, 0.f, 0.f);
  for (int s = 0; s < S; ++s) {
    const float4* pr = (const float4*)(P + (size_t)s * n + base);
    float4 a = pr[0], b = pr[1];
    tv0.x += a.x; tv0.y += a.y; tv0.z += a.z; tv0.w += a.w;
    tv1.x += b.x; tv1.y += b.y; tv1.z += b.z; tv1.w += b.w;
  }
  ((float4*)&Tl[m_loc * HDIM + o])[0] = tv0;
  ((float4*)&Tl[m_loc * HDIM + o])[1] = tv1;
  __syncthreads();

  float acc[8];
  #pragma unroll
  for (int j = 0; j < 8; ++j) acc[j] = bias[o + j];
  const float* Trow = Tl + m_loc * HDIM;
  for (int k = 0; k < HDIM; ++k) {
    float a = Trow[k];
    const float* wr = &Wl[k * HDIM + o];
    #pragma unroll
    for (int j = 0; j < 8; ++j) acc[j] = fmaf(a, wr[j], acc[j]);
  }
  float* orow = out + (size_t)m * HDIM + o;
  #pragma unroll
  for (int j = 0; j < 8; ++j) orow[j] = acc[j];
}

// ---------------------------------------------------------------------------
extern "C" void kernel_launch(void* const* d_in, const int* in_sizes, int n_in,
                              void* d_out, int out_size, void* d_ws, size_t ws_size,
                              hipStream_t stream) {
  const float* X   = (const float*)d_in[0];
  const float* W0s = (const float*)d_in[1];
  const float* W0n = (const float*)d_in[2];
  const float* W1s = (const float*)d_in[3];
  const float* W1n = (const float*)d_in[4];
  const int*   r0  = (const int*)d_in[5];
  const int*   c0  = (const int*)d_in[6];
  const float* v0  = (const float*)d_in[7];
  const int*   r1  = (const int*)d_in[8];
  const int*   c1  = (const int*)d_in[9];
  const float* v1  = (const float*)d_in[10];
  const float* gam = (const float*)d_in[11];
  const float* bet = (const float*)d_in[12];
  const float* fcW = (const float*)d_in[13];
  const float* fcb = (const float*)d_in[14];
  float* out = (float*)d_out;

  const int H = HDIM;
  const int V = in_sizes[1] / H;     // 30000
  const int B = in_sizes[0] / V;     // 2048
  const int E = in_sizes[5];         // 480000
  const int groups = (V + 31) / 32;  // 938

  // workspace layout (neigh/deg gone with the fusion)
  char* p = (char*)d_ws;
  int*   cnt0 = (int*)p;               p += (size_t)V * 4;   // memset covers cnt0+cnt1
  int*   cnt1 = (int*)p;               p += (size_t)V * 4;
  unsigned short* ph = (unsigned short*)p;  p += (size_t)groups * 4096 * 2;
  unsigned short* pl = (unsigned short*)p;  p += (size_t)groups * 4096 * 2;
  // region2: se buckets, later aliased by split-K partials P (P = 33.6 MB
  // extends past se's 30.7 MB into free workspace; nothing is placed after)
  char*  region2 = p;
  int2*  se0    = (int2*)region2;                                  // V*CAP*8
  int2*  se1    = se0 + (size_t)V * CAP;                           // V*CAP*8
  float* P      = (float*)region2;     // NSPLIT*B*H*4 = 33.6 MB

  const int S = NSPLIT;
  const int gps = (groups + S - 1) / S;

  hipMemsetAsync(cnt0, 0, (size_t)V * 2 * 4, stream);

  int eblocks = (2 * E + 255) / 256;
  bucket_kernel<<<eblocks, 256, 0, stream>>>(r0, c0, v0, r1, c1, v1,
                                             cnt0, cnt1, se0, se1, E);
  int fblocks = groups * 2;            // half-groups of 16 rows
  fused_glp_kernel<<<fblocks, 1024, 0, stream>>>(W0n, W1n, W0s, W1s,
                                                 cnt0, se0, cnt1, se1,
                                                 gam, bet, ph, pl, V);
  dim3 ggrid(B / 128, S);
  gemm_kernel<<<ggrid, 256, 0, stream>>>(X, ph, pl, P, B, V, groups, gps);
  fc_kernel<<<B / 16, 256, 0, stream>>>(P, fcW, fcb, out, B * H, S);
}